// Round 5
// baseline (679.250 us; speedup 1.0000x reference)
//
#include <hip/hip_runtime.h>
#include <math.h>
#include <stdint.h>

// ---------------- problem constants ----------------
#define CHH 100
#define CWW 152
#define NPIX 15200          // 100*152
#define NANCH 136800        // NPIX*9
#define NPRE 6000
#define NPOST 300
#define CANDCAP 8192
#define MROW 96             // u64 words per mask row (94 used, padded)

// padded pixel geometry for the MFMA conv: pp = (py+1)*154 + (px+1)
#define PSTRIDE 154
#define PPVALID 16016       // 154*104 region containing all shifted accesses
#define PPS 16128           // padded to 63 tiles of 256
#define XGUARD 256          // zero guard rows each side of the [0,PPS) range
#define XROWS_TOTAL (PPS + 2*XGUARD)   // 16640

// LDS tile inner dim: 32 halves = 4 chunks of 16B (the chunk-XOR swizzle needs exactly 4)
#define LPAD 32

// ---------------- ws layout (bytes) ----------------
#define WTH_OFF  0ull                  // w taps hi: [9][512][512] f16 = 4,718,592
#define WTL_OFF  4718592ull            // w taps lo
#define WX_OFF   9437184ull            // 1x1 weights transposed: [512][54] f32
#define XH_OFF   9547776ull            // x hi plane: [16640][512] f16 = 17,039,360
#define XL_OFF   26587136ull           // x lo plane
#define H_OFF    43626496ull           // hidden: [512][16128] f32 = 33,030,144 (reused as NMS mask)
#define ROI_OFF  76656640ull           // roi: [136800][4] f32
#define SC_OFF   78845440ull           // sc: [136800] f32
#define CTL_OFF  79392640ull           // Ctl struct
#define CAND_OFF 79396736ull           // cand: [8192] u64
#define SBOX_OFF 79462272ull           // sorted boxes: [6000] float4

typedef _Float16 f16x8 __attribute__((ext_vector_type(8)));
typedef float    f32x4 __attribute__((ext_vector_type(4)));

struct Ctl {
  unsigned hist[256];
  unsigned prefix;
  unsigned countGreater;
  unsigned candCount;
  unsigned done;
};

struct AnchorArg { float v[36]; };

__device__ __forceinline__ unsigned mono_key(float f) {
  unsigned u = __float_as_uint(f);
  return u ^ ((u & 0x80000000u) ? 0xFFFFFFFFu : 0x80000000u);
}

// async global->LDS, 16 B per lane. LDS dest semantics: wave-uniform base + lane*16.
__device__ __forceinline__ void async_copy16(void* lds, const void* g) {
  __builtin_amdgcn_global_load_lds(
      (const __attribute__((address_space(1))) unsigned int*)g,
      (__attribute__((address_space(3))) unsigned int*)lds,
      16, 0, 0);
}

// ---------------- K1: split conv1 weights into per-tap f16 hi/lo planes (+wx, +ctl init) --
__global__ __launch_bounds__(256) void prep_w_kernel(const float* __restrict__ w1,
                                                     _Float16* __restrict__ wtapH,
                                                     _Float16* __restrict__ wtapL,
                                                     const float* __restrict__ score_w,
                                                     const float* __restrict__ loc_w,
                                                     float* __restrict__ wx,
                                                     Ctl* __restrict__ ctl) {
  __shared__ float wl[4608];
  const int oc = blockIdx.x, tid = threadIdx.x;
  if (oc == 0) {
    ctl->hist[tid] = 0u;
    if (tid == 0) { ctl->prefix = 0u; ctl->countGreater = 0u; ctl->candCount = 0u; ctl->done = 0u; }
  }
  // combined 1x1 weights for this ic (=oc): wx[ic][0..53]
  if (tid < 54) wx[oc * 54 + tid] = (tid < 18) ? score_w[tid * 512 + oc] : loc_w[(tid - 18) * 512 + oc];
  for (int li = tid; li < 4608; li += 256) wl[li] = w1[(size_t)oc * 4608 + li];
  __syncthreads();
  for (int t = 0; t < 9; ++t) {
    size_t ob = ((size_t)t * 512 + oc) * 512;
    for (int ic = tid; ic < 512; ic += 256) {
      float v = wl[ic * 9 + t];
      _Float16 hi = (_Float16)v;
      wtapH[ob + ic] = hi;
      wtapL[ob + ic] = (_Float16)(v - (float)hi);
    }
  }
}

// ---------------- K2: transpose+pad+split input: x [512][15200] -> xh/xl [16640][512] ----
__global__ __launch_bounds__(256) void prep_x_kernel(const float* __restrict__ x,
                                                     _Float16* __restrict__ xh,
                                                     _Float16* __restrict__ xl) {
  __shared__ float tile[64][65];
  const int tid = threadIdx.x;
  const int r0 = blockIdx.x * 64;                // alloc-row base (0..16640)
  for (int ic0 = 0; ic0 < 512; ic0 += 64) {
    #pragma unroll
    for (int it = 0; it < 16; ++it) {
      int li = it * 256 + tid;
      int i = li >> 6, j = li & 63;
      int pp = r0 + j - XGUARD;
      float v = 0.f;
      if (pp >= 0 && pp < PPVALID) {
        int rowp = pp / PSTRIDE, colp = pp - rowp * PSTRIDE;
        if (rowp >= 1 && rowp <= 100 && colp >= 1 && colp <= 152) {
          int p = (rowp - 1) * CWW + (colp - 1);
          v = x[(size_t)(ic0 + i) * NPIX + p];
        }
      }
      tile[i][j] = v;
    }
    __syncthreads();
    int j = tid >> 2, cq = tid & 3;
    size_t ob = (size_t)(r0 + j) * 512 + ic0 + cq * 16;
    f16x8 vh0, vh1, vl0, vl1;
    #pragma unroll
    for (int c = 0; c < 8; ++c) {
      float v = tile[cq * 16 + c][j];
      _Float16 hi = (_Float16)v;
      vh0[c] = hi; vl0[c] = (_Float16)(v - (float)hi);
    }
    #pragma unroll
    for (int c = 0; c < 8; ++c) {
      float v = tile[cq * 16 + 8 + c][j];
      _Float16 hi = (_Float16)v;
      vh1[c] = hi; vl1[c] = (_Float16)(v - (float)hi);
    }
    *(f16x8*)&xh[ob]     = vh0;
    *(f16x8*)&xh[ob + 8] = vh1;
    *(f16x8*)&xl[ob]     = vl0;
    *(f16x8*)&xl[ob + 8] = vl1;
    __syncthreads();
  }
}

// ---------------- K3: conv1 as split-f16 MFMA implicit GEMM, 256x256 8-wave, split-K ----
// R4 post-mortem: 2-phase 128x128 4-wave is DUAL-pipe-bound: LDS frag traffic
// (341 B/MFMA) keeps the LDS pipe ~45-50% busy = matrix pipe busy -> ~44% ceiling
// regardless of barrier schedule (3 structures all 223-229us). Fix the RATIO:
//   - wave tile 128(oc)x64(pp): Mrep=8, Nrep=4 -> 250 B/MFMA LDS reads (-25%),
//     staging bytes/MFMA halved.
//   - block 256x256, 512 thr, 8 waves (2m x 4n); LDS 128 KB dbuf; 1 block/CU,
//     2 waves/SIMD (same as before).
//   - grid 126 would idle half the CUs -> split K (ic 0..255 / 256..511) ->
//     252 blocks; halves combined via f32 atomicAdd into zeroed h; conv bias +
//     ReLU move to heads_kernel (h's only consumer).
//   - XCD: bid%8 -> each XCD serves ONE (oc-tile,K-half) combo = 2.36 MB of
//     weights, fully L2-resident.
// Pipeline: same verified single-barrier 2-phase (stage(k+1) -> frag reads +
// 96 MFMA -> lgkm0+vmcnt0 -> barrier); per-step drain now amortized over 2x
// the MFMA work, and per-SIMD matrix (≈3725cy) > LDS (≈2290cy) -> matrix-bound.
// T2 chunk-XOR swizzle unchanged (verified 0-conflict). Mid-step
// sched_barrier(0) caps A-frag liveness (spill guard at ~230 VGPR).
__global__ __launch_bounds__(512) void conv1_mfma_kernel(const _Float16* __restrict__ xh,
                                                         const _Float16* __restrict__ xl,
                                                         const _Float16* __restrict__ wtapH,
                                                         const _Float16* __restrict__ wtapL,
                                                         float* __restrict__ h) {
  __shared__ _Float16 Ah[2][256][LPAD], Al[2][256][LPAD], Bh[2][256][LPAD], Bl[2][256][LPAD];
  const int tid = threadIdx.x;
  const int bid = blockIdx.x;
  const int oc0 = (bid & 1) * 256;               // combo = bid&3 is XCD-stable (bid%8 -> combo fixed)
  const int KH  = (bid >> 1) & 1;                // K-half: ic base
  const int pp0 = (bid >> 2) * 256;              // 63 pp tiles

  const int lane = tid & 63;
  const int n16 = lane & 15, quad = lane >> 4;
  const int wid = tid >> 6;                      // 0..7
  const int wm = wid >> 2, wn = wid & 3;         // 2m x 4n wave grid; wave tile 128oc x 64pp
  const int srow = tid >> 2, sq = tid & 3;       // staging: 128 rows per hf, 4 chunks
  const int wrow = wid << 4;                     // wave's 16-row staging base
  // T2 swizzle: LDS[row][chunk c] holds global chunk c ^ ((row>>1)&3).
  const int sqs  = sq ^ ((srow >> 1) & 3);
  const int cswz = (n16 >> 1) & 3;
  const int rdc  = (quad ^ cswz) * 8;

  const size_t thBase = (size_t)srow * 512 + (size_t)sqs * 8;

  f32x4 acc[8][4];
  #pragma unroll
  for (int mi = 0; mi < 8; ++mi)
    #pragma unroll
    for (int ni = 0; ni < 4; ++ni) acc[mi][ni] = (f32x4){0.f, 0.f, 0.f, 0.f};

  auto stageF = [&](int b, int t, int icb, int dsh) {
    const size_t wOff = ((size_t)t * 512 + oc0) * 512 + (size_t)icb;   // uniform (SALU)
    const size_t xOff = (size_t)(pp0 + dsh) * 512 + (size_t)icb;       // uniform (SALU)
    #pragma unroll
    for (int hf = 0; hf < 2; ++hf) {
      const int lrow = hf * 128 + wrow;          // wave-uniform LDS row base
      const size_t tho = thBase + (size_t)(hf * 128) * 512;
      async_copy16(&Ah[b][lrow][0], wtapH + wOff + tho);
      async_copy16(&Al[b][lrow][0], wtapL + wOff + tho);
      async_copy16(&Bh[b][lrow][0], xh + xOff + tho);
      async_copy16(&Bl[b][lrow][0], xl + xOff + tho);
    }
  };

  // K-step ks = icb_i*9 + t (72 steps of K=32 over this K-half), tap-inner.
  const int icBase = KH * 256;
  stageF(0, /*t=*/0, /*icb=*/icBase, /*dsh=*/-PSTRIDE - 1);
  int tS = 1, icbS = icBase, dshS = -PSTRIDE;    // params for stage(ks=1)

  // prologue: buf0 must be fully landed before the first frag reads
  asm volatile("s_waitcnt vmcnt(0)" ::: "memory");
  __builtin_amdgcn_sched_barrier(0);
  __builtin_amdgcn_s_barrier();
  __builtin_amdgcn_sched_barrier(0);

  for (int ks = 0; ks < 72; ++ks) {
    const int cur = ks & 1;
    if (ks + 1 < 72) {
      stageF(cur ^ 1, tS, icbS, dshS);           // issue next-step loads first
      if (++tS == 9) { tS = 0; icbS += 32; dshS = -PSTRIDE - 1; }
      else dshS += (tS == 3 || tS == 6) ? (PSTRIDE - 2) : 1;
    }

    __builtin_amdgcn_s_setprio(1);
    f16x8 bf[4], bg[4];
    #pragma unroll
    for (int ni = 0; ni < 4; ++ni) {
      bf[ni] = *(const f16x8*)&Bh[cur][wn * 64 + ni * 16 + n16][rdc];
      bg[ni] = *(const f16x8*)&Bl[cur][wn * 64 + ni * 16 + n16][rdc];
    }
    #pragma unroll
    for (int mi = 0; mi < 8; ++mi) {
      f16x8 af = *(const f16x8*)&Ah[cur][wm * 128 + mi * 16 + n16][rdc];
      f16x8 ag = *(const f16x8*)&Al[cur][wm * 128 + mi * 16 + n16][rdc];
      #pragma unroll
      for (int ni = 0; ni < 4; ++ni) {
        acc[mi][ni] = __builtin_amdgcn_mfma_f32_16x16x32_f16(af, bf[ni], acc[mi][ni], 0, 0, 0);
        acc[mi][ni] = __builtin_amdgcn_mfma_f32_16x16x32_f16(af, bg[ni], acc[mi][ni], 0, 0, 0);
        acc[mi][ni] = __builtin_amdgcn_mfma_f32_16x16x32_f16(ag, bf[ni], acc[mi][ni], 0, 0, 0);
      }
      if (mi == 3) __builtin_amdgcn_sched_barrier(0);   // liveness fence (spill guard)
    }
    __builtin_amdgcn_s_setprio(0);

    // my frag reads drained (free) + this iter's staging landed (covered by MFMA phase)
    asm volatile("s_waitcnt lgkmcnt(0) vmcnt(0)" ::: "memory");
    __builtin_amdgcn_sched_barrier(0);
    __builtin_amdgcn_s_barrier();
    __builtin_amdgcn_sched_barrier(0);
  }

  // epilogue: accumulate K-half partials (h zero-initialized on host; bias+ReLU in heads)
  #pragma unroll
  for (int mi = 0; mi < 8; ++mi) {
    int ocb = oc0 + wm * 128 + mi * 16 + quad * 4;
    #pragma unroll
    for (int ni = 0; ni < 4; ++ni) {
      int pp = pp0 + wn * 64 + ni * 16 + n16;
      #pragma unroll
      for (int r = 0; r < 4; ++r)
        atomicAdd(&h[(size_t)(ocb + r) * PPS + pp], acc[mi][ni][r]);
    }
  }
}

// ---------------- K4: 1x1 heads + softmax + loc2bbox + clip + valid ----------------
// h now holds raw split-K conv sums; conv bias + ReLU fused here at stage time.
__global__ __launch_bounds__(256) void heads_kernel(const float* __restrict__ h,
                                                    const float* __restrict__ conv_b,
                                                    const float* __restrict__ wx,
                                                    const float* __restrict__ score_b,
                                                    const float* __restrict__ loc_b,
                                                    float* __restrict__ rpn_loc,
                                                    float* __restrict__ rpn_score,
                                                    float* __restrict__ roi,
                                                    float* __restrict__ sc,
                                                    AnchorArg ab,
                                                    const int* __restrict__ ihp,
                                                    const int* __restrict__ iwp) {
  __shared__ float hs[64][64];
  __shared__ float red[54][64];
  const int tid = threadIdx.x;
  const int p0 = blockIdx.x * 64;
  const int pxl = tid & 63, icq = tid >> 6;
  int pcol = p0 + pxl;
  bool pok = pcol < NPIX;
  int ppl = 0;
  if (pok) ppl = (pcol / CWW + 1) * PSTRIDE + (pcol % CWW) + 1;

  float acc[54];
  #pragma unroll
  for (int o = 0; o < 54; ++o) acc[o] = 0.f;

  for (int c = 0; c < 8; ++c) {
    int ic0 = c * 64;
    #pragma unroll
    for (int r = 0; r < 16; ++r) {
      int i = r * 4 + icq;
      hs[i][pxl] = pok ? fmaxf(h[(size_t)(ic0 + i) * PPS + ppl] + conv_b[ic0 + i], 0.f) : 0.f;
    }
    __syncthreads();
    #pragma unroll
    for (int k = 0; k < 16; ++k) {
      int icl = icq + k * 4;
      float v = hs[icl][pxl];
      const float* wrow = &wx[(ic0 + icl) * 54];
      #pragma unroll
      for (int o = 0; o < 54; ++o) acc[o] += wrow[o] * v;
    }
    __syncthreads();
  }
  for (int w = 0; w < 4; ++w) {
    if (icq == w) {
      if (w == 0) {
        #pragma unroll
        for (int o = 0; o < 54; ++o) red[o][pxl] = acc[o];
      } else {
        #pragma unroll
        for (int o = 0; o < 54; ++o) red[o][pxl] += acc[o];
      }
    }
    __syncthreads();
  }

  const float fH = (float)(*ihp);
  const float fW = (float)(*iwp);
  for (int it = tid; it < 576; it += 256) {
    #pragma clang fp contract(off)
    int pl = it / 9, a = it - pl * 9;
    int p = p0 + pl;
    if (p >= NPIX) continue;
    float s0 = red[a * 2][pl]     + score_b[a * 2];
    float s1 = red[a * 2 + 1][pl] + score_b[a * 2 + 1];
    float dy = red[18 + a * 4][pl]     + loc_b[a * 4];
    float dx = red[18 + a * 4 + 1][pl] + loc_b[a * 4 + 1];
    float dh = red[18 + a * 4 + 2][pl] + loc_b[a * 4 + 2];
    float dw = red[18 + a * 4 + 3][pl] + loc_b[a * 4 + 3];
    int row = p * 9 + a;
    *(float2*)&rpn_score[row * 2] = make_float2(s0, s1);
    *(float4*)&rpn_loc[(size_t)row * 4] = make_float4(dy, dx, dh, dw);
    int ypix = p / CWW, xpix = p - ypix * CWW;
    float sy = (float)(ypix * 16), sx = (float)(xpix * 16);
    float a0 = sy + ab.v[a * 4 + 0], a1 = sx + ab.v[a * 4 + 1];
    float a2 = sy + ab.v[a * 4 + 2], a3 = sx + ab.v[a * 4 + 3];
    float ha = a2 - a0, wa = a3 - a1;
    float cy = a0 + 0.5f * ha, cx = a1 + 0.5f * wa;
    float cy2 = dy * ha + cy, cx2 = dx * wa + cx;
    float h2 = expf(dh) * ha, w2 = expf(dw) * wa;
    float y1 = cy2 - 0.5f * h2, x1 = cx2 - 0.5f * w2;
    float y2 = cy2 + 0.5f * h2, x2 = cx2 + 0.5f * w2;
    y1 = fminf(fmaxf(y1, 0.f), fH); x1 = fminf(fmaxf(x1, 0.f), fW);
    y2 = fminf(fmaxf(y2, 0.f), fH); x2 = fminf(fmaxf(x2, 0.f), fW);
    *(float4*)&roi[(size_t)row * 4] = make_float4(y1, x1, y2, x2);
    bool valid = (y2 - y1 >= 16.f) && (x2 - x1 >= 16.f);
    float m  = fmaxf(s0, s1);
    float e0 = expf(s0 - m), e1 = expf(s1 - m);
    float fg = e1 / (e0 + e1);
    sc[row] = valid ? fg : -__builtin_inff();
  }
}

// ---------------- K5: fused radix histogram + last-block scan ----------------
#define HGRID 120
__global__ __launch_bounds__(256) void hist_scan_kernel(const float* __restrict__ sc,
                                                        Ctl* __restrict__ ctl, int pass) {
  __shared__ unsigned hloc[256];
  __shared__ unsigned ticket_s;
  int tid = threadIdx.x;
  hloc[tid] = 0u;
  __syncthreads();
  unsigned prefix = ctl->prefix;
  for (int i = blockIdx.x * 256 + tid; i < NANCH; i += HGRID * 256) {
    unsigned m = mono_key(sc[i]);
    bool pred = (pass == 0) || ((m >> (32 - 8 * pass)) == prefix);
    if (pred) atomicAdd(&hloc[(m >> (24 - 8 * pass)) & 255u], 1u);
  }
  __syncthreads();
  if (hloc[tid]) atomicAdd(&ctl->hist[tid], hloc[tid]);
  __threadfence();
  __syncthreads();
  if (tid == 0) ticket_s = atomicAdd(&ctl->done, 1u);
  __syncthreads();
  if (ticket_s != HGRID - 1) return;
  unsigned v = atomicExch(&ctl->hist[tid], 0u);
  hloc[tid] = v;
  __syncthreads();
  for (int d = 1; d < 256; d <<= 1) {
    unsigned t2 = hloc[tid] + ((tid + d < 256) ? hloc[tid + d] : 0u);
    __syncthreads();
    hloc[tid] = t2;
    __syncthreads();
  }
  unsigned G = ctl->countGreater;
  unsigned inclT = hloc[tid];
  unsigned inclN = (tid < 255) ? hloc[tid + 1] : 0u;
  if (G + inclT >= (unsigned)NPRE && G + inclN < (unsigned)NPRE) {
    ctl->prefix = (prefix << 8) | (unsigned)tid;
    ctl->countGreater = G + inclN;
  }
  if (tid == 0) atomicExch(&ctl->done, 0u);
}

// ---------------- K6: compact candidates ----------------
__global__ __launch_bounds__(256) void compact_kernel(const float* __restrict__ sc,
                                                      Ctl* __restrict__ ctl,
                                                      unsigned long long* __restrict__ cand) {
  int i = blockIdx.x * 256 + threadIdx.x;
  unsigned prefix = ctl->prefix;
  bool pred = false; unsigned m = 0;
  if (i < NANCH) { m = mono_key(sc[i]); pred = ((m >> 8) >= prefix); }
  unsigned long long mask = __ballot(pred);
  if (mask) {
    int lane = threadIdx.x & 63;
    int leader = __ffsll((long long)mask) - 1;
    unsigned base = 0;
    if (lane == leader) base = atomicAdd(&ctl->candCount, (unsigned)__popcll(mask));
    base = __shfl(base, leader);
    if (pred) {
      unsigned slot = base + (unsigned)__popcll(mask & ((1ull << lane) - 1ull));
      if (slot < CANDCAP)
        cand[slot] = (((unsigned long long)(~m)) << 32) | (unsigned)i;
    }
  }
}

// ---------------- K7: parallel rank-scatter (replaces single-block bitonic sort) ----------
// rank(i) = #{j: key_j < key_i} over unique u64 keys == position in ascending sort.
__global__ __launch_bounds__(256) void rank_kernel(const unsigned long long* __restrict__ cand,
                                                   const Ctl* __restrict__ ctl,
                                                   const float* __restrict__ roi,
                                                   float4* __restrict__ sbox) {
  __shared__ unsigned long long kb[2048];
  __shared__ unsigned pc[64][5];
  const int tid = threadIdx.x;
  const int c = tid & 63, q = tid >> 6;
  const int slot = blockIdx.x * 64 + c;
  unsigned nv = ctl->candCount; if (nv > CANDCAP) nv = CANDCAP;
  unsigned long long K = (slot < (int)nv) ? cand[slot] : ~0ull;
  unsigned cnt = 0;
  for (unsigned c0 = 0; c0 < nv; c0 += 2048) {
    for (int i = tid; i < 2048; i += 256) {
      unsigned g = c0 + (unsigned)i;
      kb[i] = (g < nv) ? cand[g] : ~0ull;
    }
    __syncthreads();
    int lim = (int)(nv - c0); if (lim > 2048) lim = 2048;
    int i0 = q * 512, ie = i0 + 512; if (ie > lim) ie = lim;
    for (int i = i0; i < ie; ++i) cnt += (kb[i] < K) ? 1u : 0u;
    __syncthreads();
  }
  pc[c][q] = cnt;
  __syncthreads();
  if (q == 0) {
    unsigned rank = pc[c][0] + pc[c][1] + pc[c][2] + pc[c][3];
    if (slot < (int)nv && rank < NPRE) {
      unsigned idx = (unsigned)(K & 0xFFFFFFFFull);
      sbox[rank] = *(const float4*)&roi[(size_t)idx * 4];
    }
  } else if (q == 1) {
    int nvR = (nv < (unsigned)NPRE) ? (int)nv : NPRE;
    if (slot >= nvR && slot < NPRE) sbox[slot] = make_float4(0.f, 0.f, 0.f, 0.f);
  }
}

// ---------------- K8a: parallel IoU mask matrix ----------------
// One 64-thread block per upper-triangular (row-tile ci, col-tile cj) pair.
__device__ __forceinline__ bool iou_gt(float4 A, float4 B) {
  float areaA = (A.z - A.x) * (A.w - A.y);
  float areaB = (B.z - B.x) * (B.w - B.y);
  float ih = fmaxf(fminf(A.z, B.z) - fmaxf(A.x, B.x), 0.f);
  float iw = fmaxf(fminf(A.w, B.w) - fmaxf(A.y, B.y), 0.f);
  float inter = ih * iw;
  return inter / (areaA + areaB - inter + 1e-9f) > 0.7f;
}

__global__ __launch_bounds__(64) void mask_kernel(const float4* __restrict__ sbox,
                                                  unsigned long long* __restrict__ M) {
  const int ci = blockIdx.x, cj = blockIdx.y;
  if (cj < ci) return;
  __shared__ float4 cb[64];
  const int tid = threadIdx.x;
  const int i = ci * 64 + tid;
  const int jbase = cj * 64;
  const float4 bi = (i < NPRE) ? sbox[i] : make_float4(0.f, 0.f, 0.f, 0.f);
  cb[tid] = (jbase + tid < NPRE) ? sbox[jbase + tid] : make_float4(0.f, 0.f, 0.f, 0.f);
  __syncthreads();
  if (i >= NPRE) return;
  unsigned long long bits = 0ull;
  #pragma unroll 8
  for (int jj = 0; jj < 64; ++jj) {
    int jg = jbase + jj;
    float4 bj = cb[jj];
    if (jg > i && jg < NPRE && iou_gt(bi, bj)) bits |= (1ull << jj);
  }
  M[(size_t)i * MROW + cj] = bits;
}

// ---------------- K8b: serial greedy resolve ----------------
__global__ __launch_bounds__(64) void resolve_kernel(const unsigned long long* __restrict__ M,
                                                     const Ctl* __restrict__ ctl,
                                                     const float4* __restrict__ sbox,
                                                     float* __restrict__ rois_out) {
  __shared__ unsigned long long remLDS[94];
  __shared__ int keepList[NPOST];
  __shared__ int keepCount;
  const int l = threadIdx.x;
  unsigned cnt = ctl->candCount; if (cnt > (unsigned)NPRE) cnt = NPRE;
  const int nvalid = (int)cnt;

  auto initw = [&](int w) -> unsigned long long {
    int lo = w * 64;
    if (lo + 64 <= nvalid) return 0ull;
    if (lo >= nvalid) return ~0ull;
    return (~0ull) << (nvalid - lo);
  };
  unsigned long long rem0 = initw(l);
  unsigned long long rem1 = (l < 30) ? initw(64 + l) : ~0ull;

  int keepTotal = 0;
  int cstop = 94;
  unsigned long long dw = M[(size_t)l * MROW + 0];

  for (int c = 0; c < 94; ++c) {
    unsigned long long dwN = 0ull;
    if (c + 1 < 94) dwN = M[(size_t)((c + 1) * 64 + l) * MROW + (c + 1)];

    unsigned long long remRep = (c < 64) ? __shfl(rem0, c) : __shfl(rem1, c - 64);

    #pragma unroll
    for (int kk = 0; kk < 64; kk += 16) {
      unsigned long long wv[16];
      #pragma unroll
      for (int t = 0; t < 16; ++t) wv[t] = __shfl(dw, kk + t);
      #pragma unroll
      for (int t = 0; t < 16; ++t) {
        if (!((remRep >> (kk + t)) & 1ull)) remRep |= wv[t];
      }
    }

    if (l == 0) remLDS[c] = remRep;
    if (c < 64) { if (l == c) rem0 = remRep; }
    else        { if (l == c - 64) rem1 = remRep; }
    keepTotal += (int)__popcll(~remRep);

    unsigned long long km = ~remRep;
    const size_t base = (size_t)c * 64;
    while (km) {
      int k0 = __ffsll((long long)km) - 1; km &= km - 1;
      int k1 = k0, k2 = k0, k3 = k0;
      if (km) { k1 = __ffsll((long long)km) - 1; km &= km - 1; }
      if (km) { k2 = __ffsll((long long)km) - 1; km &= km - 1; }
      if (km) { k3 = __ffsll((long long)km) - 1; km &= km - 1; }
      const unsigned long long* p0 = M + (base + k0) * MROW;
      const unsigned long long* p1 = M + (base + k1) * MROW;
      const unsigned long long* p2 = M + (base + k2) * MROW;
      const unsigned long long* p3 = M + (base + k3) * MROW;
      unsigned long long a0 = p0[l], a1 = p1[l], a2 = p2[l], a3 = p3[l];
      rem0 |= a0 | a1 | a2 | a3;
      if (l < 30) {
        unsigned long long b0 = p0[64 + l], b1 = p1[64 + l], b2 = p2[64 + l], b3 = p3[64 + l];
        rem1 |= b0 | b1 | b2 | b3;
      }
    }

    dw = dwN;
    if (keepTotal >= NPOST) { cstop = c + 1; break; }
  }

  __syncthreads();
  if (l == 0) {
    int ck = 0;
    for (int w = 0; w < cstop && ck < NPOST; ++w) {
      unsigned long long kw = ~remLDS[w];
      while (kw && ck < NPOST) {
        int r = __ffsll((long long)kw) - 1; kw &= kw - 1;
        keepList[ck++] = w * 64 + r;
      }
    }
    keepCount = ck;
  }
  __syncthreads();
  for (int s = l; s < NPOST; s += 64) {
    float4 b = make_float4(0.f, 0.f, 0.f, 0.f);
    if (s < keepCount) b = sbox[keepList[s]];
    *(float4*)&rois_out[(size_t)s * 4] = b;
  }
}

// ---------------- host ----------------
extern "C" void kernel_launch(void* const* d_in, const int* in_sizes, int n_in,
                              void* d_out, int out_size, void* d_ws, size_t ws_size,
                              hipStream_t stream) {
  const float* x  = (const float*)d_in[0];
  const float* w1 = (const float*)d_in[1];
  const float* b1 = (const float*)d_in[2];
  const float* sw = (const float*)d_in[3];
  const float* sb = (const float*)d_in[4];
  const float* lw = (const float*)d_in[5];
  const float* lb = (const float*)d_in[6];
  const int* ihp  = (const int*)d_in[7];
  const int* iwp  = (const int*)d_in[8];
  float* out = (float*)d_out;

  char* ws = (char*)d_ws;
  _Float16* wtapH = (_Float16*)(ws + WTH_OFF);
  _Float16* wtapL = (_Float16*)(ws + WTL_OFF);
  float* wx   = (float*)(ws + WX_OFF);
  _Float16* xh_alloc = (_Float16*)(ws + XH_OFF);
  _Float16* xl_alloc = (_Float16*)(ws + XL_OFF);
  _Float16* xh = xh_alloc + (size_t)XGUARD * 512;
  _Float16* xl = xl_alloc + (size_t)XGUARD * 512;
  float* h    = (float*)(ws + H_OFF);
  float* roi  = (float*)(ws + ROI_OFF);
  float* sc   = (float*)(ws + SC_OFF);
  Ctl*   ctl  = (Ctl*)(ws + CTL_OFF);
  unsigned long long* cand = (unsigned long long*)(ws + CAND_OFF);
  float4* sbox = (float4*)(ws + SBOX_OFF);
  unsigned long long* Mmask = (unsigned long long*)(ws + H_OFF);

  AnchorArg ab;
  {
    const double ratios[3] = {0.5, 1.0, 2.0};
    const double scales[3] = {8.0, 16.0, 32.0};
    for (int i = 0; i < 3; ++i)
      for (int j = 0; j < 3; ++j) {
        double hh = 16.0 * scales[j] * sqrt(ratios[i]);
        double wwd = 16.0 * scales[j] * sqrt(1.0 / ratios[i]);
        int a = i * 3 + j;
        ab.v[a * 4 + 0] = (float)(8.0 - hh / 2.0);
        ab.v[a * 4 + 1] = (float)(8.0 - wwd / 2.0);
        ab.v[a * 4 + 2] = (float)(8.0 + hh / 2.0);
        ab.v[a * 4 + 3] = (float)(8.0 + wwd / 2.0);
      }
  }

  float* rpn_loc   = out;                 // 136800*4
  float* rpn_score = out + 547200;        // 136800*2
  float* rois      = out + 820800;        // 300*4

  prep_w_kernel<<<512, 256, 0, stream>>>(w1, wtapH, wtapL, sw, lw, wx, ctl);
  prep_x_kernel<<<XROWS_TOTAL / 64, 256, 0, stream>>>(x, xh_alloc, xl_alloc);
  hipMemsetAsync(h, 0, (size_t)512 * PPS * sizeof(float), stream);   // split-K accumulator
  conv1_mfma_kernel<<<252, 512, 0, stream>>>(xh, xl, wtapH, wtapL, h);
  heads_kernel<<<238, 256, 0, stream>>>(h, b1, wx, sb, lb, rpn_loc, rpn_score, roi, sc, ab, ihp, iwp);
  for (int p = 0; p < 3; ++p)
    hist_scan_kernel<<<HGRID, 256, 0, stream>>>(sc, ctl, p);
  compact_kernel<<<535, 256, 0, stream>>>(sc, ctl, cand);
  rank_kernel<<<CANDCAP / 64, 256, 0, stream>>>(cand, ctl, roi, sbox);
  mask_kernel<<<dim3(94, 94), 64, 0, stream>>>(sbox, Mmask);
  resolve_kernel<<<1, 64, 0, stream>>>(Mmask, ctl, sbox, rois);
}

// Round 6
// 637.868 us; speedup vs baseline: 1.0649x; 1.0649x over previous
//
#include <hip/hip_runtime.h>
#include <math.h>
#include <stdint.h>

// ---------------- problem constants ----------------
#define CHH 100
#define CWW 152
#define NPIX 15200          // 100*152
#define NANCH 136800        // NPIX*9
#define NPRE 6000
#define NPOST 300
#define CANDCAP 8192
#define MROW 96             // u64 words per mask row (94 used, padded)

// padded pixel geometry for the MFMA conv: pp = (py+1)*154 + (px+1)
#define PSTRIDE 154
#define PPVALID 16016       // 154*104 region containing all shifted accesses
#define PPS 16128           // padded to 126 tiles of 128
#define XGUARD 256          // zero guard rows each side of the [0,PPS) range
#define XROWS_TOTAL (PPS + 2*XGUARD)   // 16640

// LDS tile inner dim: 32 halves = 4 chunks of 16B (the chunk-XOR swizzle needs exactly 4)
#define LPAD 32

// ---------------- ws layout (bytes) ----------------
#define WTH_OFF  0ull                  // w taps hi: [9][512][512] f16 = 4,718,592
#define WTL_OFF  4718592ull            // w taps lo
#define WX_OFF   9437184ull            // 1x1 weights transposed: [512][54] f32
#define XH_OFF   9547776ull            // x hi plane: [16640][512] f16 = 17,039,360
#define XL_OFF   26587136ull           // x lo plane
#define H_OFF    43626496ull           // hidden: [512][16128] f32 = 33,030,144 (reused as NMS mask)
#define ROI_OFF  76656640ull           // roi: [136800][4] f32
#define SC_OFF   78845440ull           // sc: [136800] f32
#define CTL_OFF  79392640ull           // Ctl struct
#define CAND_OFF 79396736ull           // cand: [8192] u64
#define SBOX_OFF 79462272ull           // sorted boxes: [6000] float4

typedef _Float16 f16x8 __attribute__((ext_vector_type(8)));
typedef float    f32x4 __attribute__((ext_vector_type(4)));

struct Ctl {
  unsigned hist[256];
  unsigned prefix;
  unsigned countGreater;
  unsigned candCount;
  unsigned done;
};

struct AnchorArg { float v[36]; };

__device__ __forceinline__ unsigned mono_key(float f) {
  unsigned u = __float_as_uint(f);
  return u ^ ((u & 0x80000000u) ? 0xFFFFFFFFu : 0x80000000u);
}

// async global->LDS, 16 B per lane. LDS dest semantics: wave-uniform base + lane*16.
__device__ __forceinline__ void async_copy16(void* lds, const void* g) {
  __builtin_amdgcn_global_load_lds(
      (const __attribute__((address_space(1))) unsigned int*)g,
      (__attribute__((address_space(3))) unsigned int*)lds,
      16, 0, 0);
}

// ---------------- K1: split conv1 weights into per-tap f16 hi/lo planes (+wx, +ctl init) --
__global__ __launch_bounds__(256) void prep_w_kernel(const float* __restrict__ w1,
                                                     _Float16* __restrict__ wtapH,
                                                     _Float16* __restrict__ wtapL,
                                                     const float* __restrict__ score_w,
                                                     const float* __restrict__ loc_w,
                                                     float* __restrict__ wx,
                                                     Ctl* __restrict__ ctl) {
  __shared__ float wl[4608];
  const int oc = blockIdx.x, tid = threadIdx.x;
  if (oc == 0) {
    ctl->hist[tid] = 0u;
    if (tid == 0) { ctl->prefix = 0u; ctl->countGreater = 0u; ctl->candCount = 0u; ctl->done = 0u; }
  }
  // combined 1x1 weights for this ic (=oc): wx[ic][0..53]
  if (tid < 54) wx[oc * 54 + tid] = (tid < 18) ? score_w[tid * 512 + oc] : loc_w[(tid - 18) * 512 + oc];
  for (int li = tid; li < 4608; li += 256) wl[li] = w1[(size_t)oc * 4608 + li];
  __syncthreads();
  for (int t = 0; t < 9; ++t) {
    size_t ob = ((size_t)t * 512 + oc) * 512;
    for (int ic = tid; ic < 512; ic += 256) {
      float v = wl[ic * 9 + t];
      _Float16 hi = (_Float16)v;
      wtapH[ob + ic] = hi;
      wtapL[ob + ic] = (_Float16)(v - (float)hi);
    }
  }
}

// ---------------- K2: transpose+pad+split input: x [512][15200] -> xh/xl [16640][512] ----
__global__ __launch_bounds__(256) void prep_x_kernel(const float* __restrict__ x,
                                                     _Float16* __restrict__ xh,
                                                     _Float16* __restrict__ xl) {
  __shared__ float tile[64][65];
  const int tid = threadIdx.x;
  const int r0 = blockIdx.x * 64;                // alloc-row base (0..16640)
  for (int ic0 = 0; ic0 < 512; ic0 += 64) {
    #pragma unroll
    for (int it = 0; it < 16; ++it) {
      int li = it * 256 + tid;
      int i = li >> 6, j = li & 63;
      int pp = r0 + j - XGUARD;
      float v = 0.f;
      if (pp >= 0 && pp < PPVALID) {
        int rowp = pp / PSTRIDE, colp = pp - rowp * PSTRIDE;
        if (rowp >= 1 && rowp <= 100 && colp >= 1 && colp <= 152) {
          int p = (rowp - 1) * CWW + (colp - 1);
          v = x[(size_t)(ic0 + i) * NPIX + p];
        }
      }
      tile[i][j] = v;
    }
    __syncthreads();
    int j = tid >> 2, cq = tid & 3;
    size_t ob = (size_t)(r0 + j) * 512 + ic0 + cq * 16;
    f16x8 vh0, vh1, vl0, vl1;
    #pragma unroll
    for (int c = 0; c < 8; ++c) {
      float v = tile[cq * 16 + c][j];
      _Float16 hi = (_Float16)v;
      vh0[c] = hi; vl0[c] = (_Float16)(v - (float)hi);
    }
    #pragma unroll
    for (int c = 0; c < 8; ++c) {
      float v = tile[cq * 16 + 8 + c][j];
      _Float16 hi = (_Float16)v;
      vh1[c] = hi; vl1[c] = (_Float16)(v - (float)hi);
    }
    *(f16x8*)&xh[ob]     = vh0;
    *(f16x8*)&xh[ob + 8] = vh1;
    *(f16x8*)&xl[ob]     = vl0;
    *(f16x8*)&xl[ob + 8] = vl1;
    __syncthreads();
  }
}

// ---------------- K3: conv1 as split-f16 MFMA implicit GEMM ----------------
// REVERTED to the R2 proven-best structure (223 us, MfmaUtil 44.9, 0 bank
// conflicts): 128x128 tile, 4 waves, 2 blocks/CU (cross-block overlap fills
// the drain gaps - m114; R5's 256x256 1-block/CU lost 29 us by removing it).
// Counted-vmcnt pipelined K-loop (T3/T4): raw s_barrier (NO vmcnt drain),
// s_waitcnt vmcnt(8) keeps the 8 just-issued next-step loads in flight across
// the barrier. Second raw barrier after frag ds_reads + lgkmcnt(0), BEFORE the
// MFMAs. T5 setprio around the MFMA cluster. T2 chunk-XOR swizzle.
__global__ __launch_bounds__(256) void conv1_mfma_kernel(const _Float16* __restrict__ xh,
                                                         const _Float16* __restrict__ xl,
                                                         const _Float16* __restrict__ wtapH,
                                                         const _Float16* __restrict__ wtapL,
                                                         const float* __restrict__ bias,
                                                         float* __restrict__ h) {
  __shared__ _Float16 Ah[2][128][LPAD], Al[2][128][LPAD], Bh[2][128][LPAD], Bl[2][128][LPAD];
  __shared__ float bsm[128];
  const int tid = threadIdx.x;
  const int bid = blockIdx.x;
  const int oc0 = (bid & 3) * 128;
  const int pp0 = (((bid >> 3) << 1) + ((bid >> 2) & 1)) * 128;
  if (tid < 128) bsm[tid] = bias[oc0 + tid];

  const int lane = tid & 63;
  const int n16 = lane & 15, quad = lane >> 4;
  const int wid = tid >> 6;
  const int wm = wid >> 1, wn = wid & 1;
  const int srow = tid >> 2, sq = tid & 3;
  const int wrow = wid << 4;                     // this wave's LDS staging row base
  // T2 swizzle: LDS[row][chunk c] holds global chunk c ^ ((row>>1)&3).
  const int sqs  = sq ^ ((srow >> 1) & 3);       // staging-side source chunk (per-thread const)
  const int cswz = (n16 >> 1) & 3;               // read-side chunk XOR (per-thread const)
  const int rdc  = (quad ^ cswz) * 8;            // halves offset of this lane's fragment chunk

  // per-thread global source offset (halves), loop-invariant
  const size_t thBase = (size_t)srow * 512 + (size_t)sqs * 8;

  f32x4 acc[4][4];
  #pragma unroll
  for (int mi = 0; mi < 4; ++mi)
    #pragma unroll
    for (int ni = 0; ni < 4; ++ni) acc[mi][ni] = (f32x4){0.f, 0.f, 0.f, 0.f};

  auto stageF = [&](int b, int t, int icb, int dsh) {
    const size_t wOff = ((size_t)t * 512 + oc0) * 512 + (size_t)icb;   // uniform (SALU)
    const size_t xOff = (size_t)(pp0 + dsh) * 512 + (size_t)icb;       // uniform (SALU)
    #pragma unroll
    for (int hf = 0; hf < 2; ++hf) {
      const int lrow = hf * 64 + wrow;           // wave-uniform LDS row base
      const size_t tho = thBase + (size_t)(hf * 64) * 512;
      async_copy16(&Ah[b][lrow][0], wtapH + wOff + tho);
      async_copy16(&Al[b][lrow][0], wtapL + wOff + tho);
      async_copy16(&Bh[b][lrow][0], xh + xOff + tho);
      async_copy16(&Bl[b][lrow][0], xl + xOff + tho);
    }
  };

  // K-step ks = icb_i*9 + t (144 steps of K=32), tap-inner for L2 reuse.
  stageF(0, /*t=*/0, /*icb=*/0, /*dsh=*/-PSTRIDE - 1);
  int tS = 1, icbS = 0, dshS = -PSTRIDE;         // params for stage(ks=1)

  for (int ks = 0; ks < 144; ++ks) {
    const int cur = ks & 1;
    if (ks + 1 < 144) {
      stageF(cur ^ 1, tS, icbS, dshS);
      if (++tS == 9) { tS = 0; icbS += 32; dshS = -PSTRIDE - 1; }
      else dshS += (tS == 3 || tS == 6) ? (PSTRIDE - 2) : 1;
      asm volatile("s_waitcnt vmcnt(8)" ::: "memory");   // cur's 8 loads done; next 8 in flight
    } else {
      asm volatile("s_waitcnt vmcnt(0)" ::: "memory");   // final step: drain
    }
    __builtin_amdgcn_sched_barrier(0);
    __builtin_amdgcn_s_barrier();                         // buf[cur] ready for all waves
    __builtin_amdgcn_sched_barrier(0);

    f16x8 af[4], ag[4], bf[4], bg[4];
    #pragma unroll
    for (int mi = 0; mi < 4; ++mi) {
      af[mi] = *(const f16x8*)&Ah[cur][wm * 64 + mi * 16 + n16][rdc];
      ag[mi] = *(const f16x8*)&Al[cur][wm * 64 + mi * 16 + n16][rdc];
    }
    #pragma unroll
    for (int ni = 0; ni < 4; ++ni) {
      bf[ni] = *(const f16x8*)&Bh[cur][wn * 64 + ni * 16 + n16][rdc];
      bg[ni] = *(const f16x8*)&Bl[cur][wn * 64 + ni * 16 + n16][rdc];
    }
    asm volatile("s_waitcnt lgkmcnt(0)" ::: "memory");    // frag reads drained...
    __builtin_amdgcn_sched_barrier(0);
    __builtin_amdgcn_s_barrier();                         // ...so buf[cur] may be overwritten next iter
    __builtin_amdgcn_sched_barrier(0);

    __builtin_amdgcn_s_setprio(1);
    #pragma unroll
    for (int mi = 0; mi < 4; ++mi)
      #pragma unroll
      for (int ni = 0; ni < 4; ++ni) {
        acc[mi][ni] = __builtin_amdgcn_mfma_f32_16x16x32_f16(af[mi], bf[ni], acc[mi][ni], 0, 0, 0);
        acc[mi][ni] = __builtin_amdgcn_mfma_f32_16x16x32_f16(af[mi], bg[ni], acc[mi][ni], 0, 0, 0);
        acc[mi][ni] = __builtin_amdgcn_mfma_f32_16x16x32_f16(ag[mi], bf[ni], acc[mi][ni], 0, 0, 0);
      }
    __builtin_amdgcn_s_setprio(0);
  }

  #pragma unroll
  for (int mi = 0; mi < 4; ++mi) {
    int ocb = wm * 64 + mi * 16 + quad * 4;
    #pragma unroll
    for (int ni = 0; ni < 4; ++ni) {
      int pp = pp0 + wn * 64 + ni * 16 + n16;
      #pragma unroll
      for (int r = 0; r < 4; ++r) {
        float v = acc[mi][ni][r] + bsm[ocb + r];
        h[(size_t)(oc0 + ocb + r) * PPS + pp] = fmaxf(v, 0.f);
      }
    }
  }
}

// ---------------- K4: 1x1 heads + softmax + loc2bbox + clip + valid ----------------
// icq is wave-uniform (tid>>6 = wave id) but the compiler can't prove it ->
// the 54 wx loads per k-iter were emitted as per-lane VMEM. readfirstlane
// makes the weight-row address scalar -> s_load_dwordx16 on the SMEM pipe,
// leaving the inner loop VALU-bound (~108 cyc/k instead of ~450).
__global__ __launch_bounds__(256) void heads_kernel(const float* __restrict__ h,
                                                    const float* __restrict__ wx,
                                                    const float* __restrict__ score_b,
                                                    const float* __restrict__ loc_b,
                                                    float* __restrict__ rpn_loc,
                                                    float* __restrict__ rpn_score,
                                                    float* __restrict__ roi,
                                                    float* __restrict__ sc,
                                                    AnchorArg ab,
                                                    const int* __restrict__ ihp,
                                                    const int* __restrict__ iwp) {
  __shared__ float hs[64][64];
  __shared__ float red[54][64];
  const int tid = threadIdx.x;
  const int p0 = blockIdx.x * 64;
  const int pxl = tid & 63, icq = tid >> 6;
  const int icu = __builtin_amdgcn_readfirstlane(icq);   // provably wave-uniform
  int pcol = p0 + pxl;
  bool pok = pcol < NPIX;
  int ppl = 0;
  if (pok) ppl = (pcol / CWW + 1) * PSTRIDE + (pcol % CWW) + 1;

  float acc[54];
  #pragma unroll
  for (int o = 0; o < 54; ++o) acc[o] = 0.f;

  for (int c = 0; c < 8; ++c) {
    int ic0 = c * 64;
    #pragma unroll
    for (int r = 0; r < 16; ++r) {
      int i = r * 4 + icq;
      hs[i][pxl] = pok ? h[(size_t)(ic0 + i) * PPS + ppl] : 0.f;
    }
    __syncthreads();
    #pragma unroll
    for (int k = 0; k < 16; ++k) {
      int icl = icu + k * 4;                     // wave-uniform (SGPR)
      float v = hs[icl][pxl];
      const float* wrow = &wx[(ic0 + icl) * 54]; // scalar address -> s_load
      #pragma unroll
      for (int o = 0; o < 54; ++o) acc[o] += wrow[o] * v;
    }
    __syncthreads();
  }
  for (int w = 0; w < 4; ++w) {
    if (icq == w) {
      if (w == 0) {
        #pragma unroll
        for (int o = 0; o < 54; ++o) red[o][pxl] = acc[o];
      } else {
        #pragma unroll
        for (int o = 0; o < 54; ++o) red[o][pxl] += acc[o];
      }
    }
    __syncthreads();
  }

  const float fH = (float)(*ihp);
  const float fW = (float)(*iwp);
  for (int it = tid; it < 576; it += 256) {
    #pragma clang fp contract(off)
    int pl = it / 9, a = it - pl * 9;
    int p = p0 + pl;
    if (p >= NPIX) continue;
    float s0 = red[a * 2][pl]     + score_b[a * 2];
    float s1 = red[a * 2 + 1][pl] + score_b[a * 2 + 1];
    float dy = red[18 + a * 4][pl]     + loc_b[a * 4];
    float dx = red[18 + a * 4 + 1][pl] + loc_b[a * 4 + 1];
    float dh = red[18 + a * 4 + 2][pl] + loc_b[a * 4 + 2];
    float dw = red[18 + a * 4 + 3][pl] + loc_b[a * 4 + 3];
    int row = p * 9 + a;
    *(float2*)&rpn_score[row * 2] = make_float2(s0, s1);
    *(float4*)&rpn_loc[(size_t)row * 4] = make_float4(dy, dx, dh, dw);
    int ypix = p / CWW, xpix = p - ypix * CWW;
    float sy = (float)(ypix * 16), sx = (float)(xpix * 16);
    float a0 = sy + ab.v[a * 4 + 0], a1 = sx + ab.v[a * 4 + 1];
    float a2 = sy + ab.v[a * 4 + 2], a3 = sx + ab.v[a * 4 + 3];
    float ha = a2 - a0, wa = a3 - a1;
    float cy = a0 + 0.5f * ha, cx = a1 + 0.5f * wa;
    float cy2 = dy * ha + cy, cx2 = dx * wa + cx;
    float h2 = expf(dh) * ha, w2 = expf(dw) * wa;
    float y1 = cy2 - 0.5f * h2, x1 = cx2 - 0.5f * w2;
    float y2 = cy2 + 0.5f * h2, x2 = cx2 + 0.5f * w2;
    y1 = fminf(fmaxf(y1, 0.f), fH); x1 = fminf(fmaxf(x1, 0.f), fW);
    y2 = fminf(fmaxf(y2, 0.f), fH); x2 = fminf(fmaxf(x2, 0.f), fW);
    *(float4*)&roi[(size_t)row * 4] = make_float4(y1, x1, y2, x2);
    bool valid = (y2 - y1 >= 16.f) && (x2 - x1 >= 16.f);
    float m  = fmaxf(s0, s1);
    float e0 = expf(s0 - m), e1 = expf(s1 - m);
    float fg = e1 / (e0 + e1);
    sc[row] = valid ? fg : -__builtin_inff();
  }
}

// ---------------- K5: fused radix histogram + last-block scan ----------------
#define HGRID 120
__global__ __launch_bounds__(256) void hist_scan_kernel(const float* __restrict__ sc,
                                                        Ctl* __restrict__ ctl, int pass) {
  __shared__ unsigned hloc[256];
  __shared__ unsigned ticket_s;
  int tid = threadIdx.x;
  hloc[tid] = 0u;
  __syncthreads();
  unsigned prefix = ctl->prefix;
  for (int i = blockIdx.x * 256 + tid; i < NANCH; i += HGRID * 256) {
    unsigned m = mono_key(sc[i]);
    bool pred = (pass == 0) || ((m >> (32 - 8 * pass)) == prefix);
    if (pred) atomicAdd(&hloc[(m >> (24 - 8 * pass)) & 255u], 1u);
  }
  __syncthreads();
  if (hloc[tid]) atomicAdd(&ctl->hist[tid], hloc[tid]);
  __threadfence();
  __syncthreads();
  if (tid == 0) ticket_s = atomicAdd(&ctl->done, 1u);
  __syncthreads();
  if (ticket_s != HGRID - 1) return;
  unsigned v = atomicExch(&ctl->hist[tid], 0u);
  hloc[tid] = v;
  __syncthreads();
  for (int d = 1; d < 256; d <<= 1) {
    unsigned t2 = hloc[tid] + ((tid + d < 256) ? hloc[tid + d] : 0u);
    __syncthreads();
    hloc[tid] = t2;
    __syncthreads();
  }
  unsigned G = ctl->countGreater;
  unsigned inclT = hloc[tid];
  unsigned inclN = (tid < 255) ? hloc[tid + 1] : 0u;
  if (G + inclT >= (unsigned)NPRE && G + inclN < (unsigned)NPRE) {
    ctl->prefix = (prefix << 8) | (unsigned)tid;
    ctl->countGreater = G + inclN;
  }
  if (tid == 0) atomicExch(&ctl->done, 0u);
}

// ---------------- K6: compact candidates ----------------
__global__ __launch_bounds__(256) void compact_kernel(const float* __restrict__ sc,
                                                      Ctl* __restrict__ ctl,
                                                      unsigned long long* __restrict__ cand) {
  int i = blockIdx.x * 256 + threadIdx.x;
  unsigned prefix = ctl->prefix;
  bool pred = false; unsigned m = 0;
  if (i < NANCH) { m = mono_key(sc[i]); pred = ((m >> 8) >= prefix); }
  unsigned long long mask = __ballot(pred);
  if (mask) {
    int lane = threadIdx.x & 63;
    int leader = __ffsll((long long)mask) - 1;
    unsigned base = 0;
    if (lane == leader) base = atomicAdd(&ctl->candCount, (unsigned)__popcll(mask));
    base = __shfl(base, leader);
    if (pred) {
      unsigned slot = base + (unsigned)__popcll(mask & ((1ull << lane) - 1ull));
      if (slot < CANDCAP)
        cand[slot] = (((unsigned long long)(~m)) << 32) | (unsigned)i;
    }
  }
}

// ---------------- K7: parallel rank-scatter (replaces single-block bitonic sort) ----------
// rank(i) = #{j: key_j < key_i} over unique u64 keys == position in ascending sort.
__global__ __launch_bounds__(256) void rank_kernel(const unsigned long long* __restrict__ cand,
                                                   const Ctl* __restrict__ ctl,
                                                   const float* __restrict__ roi,
                                                   float4* __restrict__ sbox) {
  __shared__ unsigned long long kb[2048];
  __shared__ unsigned pc[64][5];
  const int tid = threadIdx.x;
  const int c = tid & 63, q = tid >> 6;
  const int slot = blockIdx.x * 64 + c;
  unsigned nv = ctl->candCount; if (nv > CANDCAP) nv = CANDCAP;
  unsigned long long K = (slot < (int)nv) ? cand[slot] : ~0ull;
  unsigned cnt = 0;
  for (unsigned c0 = 0; c0 < nv; c0 += 2048) {
    for (int i = tid; i < 2048; i += 256) {
      unsigned g = c0 + (unsigned)i;
      kb[i] = (g < nv) ? cand[g] : ~0ull;
    }
    __syncthreads();
    int lim = (int)(nv - c0); if (lim > 2048) lim = 2048;
    int i0 = q * 512, ie = i0 + 512; if (ie > lim) ie = lim;
    for (int i = i0; i < ie; ++i) cnt += (kb[i] < K) ? 1u : 0u;
    __syncthreads();
  }
  pc[c][q] = cnt;
  __syncthreads();
  if (q == 0) {
    unsigned rank = pc[c][0] + pc[c][1] + pc[c][2] + pc[c][3];
    if (slot < (int)nv && rank < NPRE) {
      unsigned idx = (unsigned)(K & 0xFFFFFFFFull);
      sbox[rank] = *(const float4*)&roi[(size_t)idx * 4];
    }
  } else if (q == 1) {
    int nvR = (nv < (unsigned)NPRE) ? (int)nv : NPRE;
    if (slot >= nvR && slot < NPRE) sbox[slot] = make_float4(0.f, 0.f, 0.f, 0.f);
  }
}

// ---------------- K8a: parallel IoU mask matrix ----------------
// One 64-thread block per upper-triangular (row-tile ci, col-tile cj) pair.
__device__ __forceinline__ bool iou_gt(float4 A, float4 B) {
  float areaA = (A.z - A.x) * (A.w - A.y);
  float areaB = (B.z - B.x) * (B.w - B.y);
  float ih = fmaxf(fminf(A.z, B.z) - fmaxf(A.x, B.x), 0.f);
  float iw = fmaxf(fminf(A.w, B.w) - fmaxf(A.y, B.y), 0.f);
  float inter = ih * iw;
  return inter / (areaA + areaB - inter + 1e-9f) > 0.7f;
}

__global__ __launch_bounds__(64) void mask_kernel(const float4* __restrict__ sbox,
                                                  unsigned long long* __restrict__ M) {
  const int ci = blockIdx.x, cj = blockIdx.y;
  if (cj < ci) return;
  __shared__ float4 cb[64];
  const int tid = threadIdx.x;
  const int i = ci * 64 + tid;
  const int jbase = cj * 64;
  const float4 bi = (i < NPRE) ? sbox[i] : make_float4(0.f, 0.f, 0.f, 0.f);
  cb[tid] = (jbase + tid < NPRE) ? sbox[jbase + tid] : make_float4(0.f, 0.f, 0.f, 0.f);
  __syncthreads();
  if (i >= NPRE) return;
  unsigned long long bits = 0ull;
  #pragma unroll 8
  for (int jj = 0; jj < 64; ++jj) {
    int jg = jbase + jj;
    float4 bj = cb[jj];
    if (jg > i && jg < NPRE && iou_gt(bi, bj)) bits |= (1ull << jj);
  }
  M[(size_t)i * MROW + cj] = bits;
}

// ---------------- K8b: serial greedy resolve ----------------
__global__ __launch_bounds__(64) void resolve_kernel(const unsigned long long* __restrict__ M,
                                                     const Ctl* __restrict__ ctl,
                                                     const float4* __restrict__ sbox,
                                                     float* __restrict__ rois_out) {
  __shared__ unsigned long long remLDS[94];
  __shared__ int keepList[NPOST];
  __shared__ int keepCount;
  const int l = threadIdx.x;
  unsigned cnt = ctl->candCount; if (cnt > (unsigned)NPRE) cnt = NPRE;
  const int nvalid = (int)cnt;

  auto initw = [&](int w) -> unsigned long long {
    int lo = w * 64;
    if (lo + 64 <= nvalid) return 0ull;
    if (lo >= nvalid) return ~0ull;
    return (~0ull) << (nvalid - lo);
  };
  unsigned long long rem0 = initw(l);
  unsigned long long rem1 = (l < 30) ? initw(64 + l) : ~0ull;

  int keepTotal = 0;
  int cstop = 94;
  unsigned long long dw = M[(size_t)l * MROW + 0];

  for (int c = 0; c < 94; ++c) {
    unsigned long long dwN = 0ull;
    if (c + 1 < 94) dwN = M[(size_t)((c + 1) * 64 + l) * MROW + (c + 1)];

    unsigned long long remRep = (c < 64) ? __shfl(rem0, c) : __shfl(rem1, c - 64);

    #pragma unroll
    for (int kk = 0; kk < 64; kk += 16) {
      unsigned long long wv[16];
      #pragma unroll
      for (int t = 0; t < 16; ++t) wv[t] = __shfl(dw, kk + t);
      #pragma unroll
      for (int t = 0; t < 16; ++t) {
        if (!((remRep >> (kk + t)) & 1ull)) remRep |= wv[t];
      }
    }

    if (l == 0) remLDS[c] = remRep;
    if (c < 64) { if (l == c) rem0 = remRep; }
    else        { if (l == c - 64) rem1 = remRep; }
    keepTotal += (int)__popcll(~remRep);

    unsigned long long km = ~remRep;
    const size_t base = (size_t)c * 64;
    while (km) {
      int k0 = __ffsll((long long)km) - 1; km &= km - 1;
      int k1 = k0, k2 = k0, k3 = k0;
      if (km) { k1 = __ffsll((long long)km) - 1; km &= km - 1; }
      if (km) { k2 = __ffsll((long long)km) - 1; km &= km - 1; }
      if (km) { k3 = __ffsll((long long)km) - 1; km &= km - 1; }
      const unsigned long long* p0 = M + (base + k0) * MROW;
      const unsigned long long* p1 = M + (base + k1) * MROW;
      const unsigned long long* p2 = M + (base + k2) * MROW;
      const unsigned long long* p3 = M + (base + k3) * MROW;
      unsigned long long a0 = p0[l], a1 = p1[l], a2 = p2[l], a3 = p3[l];
      rem0 |= a0 | a1 | a2 | a3;
      if (l < 30) {
        unsigned long long b0 = p0[64 + l], b1 = p1[64 + l], b2 = p2[64 + l], b3 = p3[64 + l];
        rem1 |= b0 | b1 | b2 | b3;
      }
    }

    dw = dwN;
    if (keepTotal >= NPOST) { cstop = c + 1; break; }
  }

  __syncthreads();
  if (l == 0) {
    int ck = 0;
    for (int w = 0; w < cstop && ck < NPOST; ++w) {
      unsigned long long kw = ~remLDS[w];
      while (kw && ck < NPOST) {
        int r = __ffsll((long long)kw) - 1; kw &= kw - 1;
        keepList[ck++] = w * 64 + r;
      }
    }
    keepCount = ck;
  }
  __syncthreads();
  for (int s = l; s < NPOST; s += 64) {
    float4 b = make_float4(0.f, 0.f, 0.f, 0.f);
    if (s < keepCount) b = sbox[keepList[s]];
    *(float4*)&rois_out[(size_t)s * 4] = b;
  }
}

// ---------------- host ----------------
extern "C" void kernel_launch(void* const* d_in, const int* in_sizes, int n_in,
                              void* d_out, int out_size, void* d_ws, size_t ws_size,
                              hipStream_t stream) {
  const float* x  = (const float*)d_in[0];
  const float* w1 = (const float*)d_in[1];
  const float* b1 = (const float*)d_in[2];
  const float* sw = (const float*)d_in[3];
  const float* sb = (const float*)d_in[4];
  const float* lw = (const float*)d_in[5];
  const float* lb = (const float*)d_in[6];
  const int* ihp  = (const int*)d_in[7];
  const int* iwp  = (const int*)d_in[8];
  float* out = (float*)d_out;

  char* ws = (char*)d_ws;
  _Float16* wtapH = (_Float16*)(ws + WTH_OFF);
  _Float16* wtapL = (_Float16*)(ws + WTL_OFF);
  float* wx   = (float*)(ws + WX_OFF);
  _Float16* xh_alloc = (_Float16*)(ws + XH_OFF);
  _Float16* xl_alloc = (_Float16*)(ws + XL_OFF);
  _Float16* xh = xh_alloc + (size_t)XGUARD * 512;
  _Float16* xl = xl_alloc + (size_t)XGUARD * 512;
  float* h    = (float*)(ws + H_OFF);
  float* roi  = (float*)(ws + ROI_OFF);
  float* sc   = (float*)(ws + SC_OFF);
  Ctl*   ctl  = (Ctl*)(ws + CTL_OFF);
  unsigned long long* cand = (unsigned long long*)(ws + CAND_OFF);
  float4* sbox = (float4*)(ws + SBOX_OFF);
  unsigned long long* Mmask = (unsigned long long*)(ws + H_OFF);

  AnchorArg ab;
  {
    const double ratios[3] = {0.5, 1.0, 2.0};
    const double scales[3] = {8.0, 16.0, 32.0};
    for (int i = 0; i < 3; ++i)
      for (int j = 0; j < 3; ++j) {
        double hh = 16.0 * scales[j] * sqrt(ratios[i]);
        double wwd = 16.0 * scales[j] * sqrt(1.0 / ratios[i]);
        int a = i * 3 + j;
        ab.v[a * 4 + 0] = (float)(8.0 - hh / 2.0);
        ab.v[a * 4 + 1] = (float)(8.0 - wwd / 2.0);
        ab.v[a * 4 + 2] = (float)(8.0 + hh / 2.0);
        ab.v[a * 4 + 3] = (float)(8.0 + wwd / 2.0);
      }
  }

  float* rpn_loc   = out;                 // 136800*4
  float* rpn_score = out + 547200;        // 136800*2
  float* rois      = out + 820800;        // 300*4

  prep_w_kernel<<<512, 256, 0, stream>>>(w1, wtapH, wtapL, sw, lw, wx, ctl);
  prep_x_kernel<<<XROWS_TOTAL / 64, 256, 0, stream>>>(x, xh_alloc, xl_alloc);
  conv1_mfma_kernel<<<504, 256, 0, stream>>>(xh, xl, wtapH, wtapL, b1, h);
  heads_kernel<<<238, 256, 0, stream>>>(h, wx, sb, lb, rpn_loc, rpn_score, roi, sc, ab, ihp, iwp);
  for (int p = 0; p < 3; ++p)
    hist_scan_kernel<<<HGRID, 256, 0, stream>>>(sc, ctl, p);
  compact_kernel<<<535, 256, 0, stream>>>(sc, ctl, cand);
  rank_kernel<<<CANDCAP / 64, 256, 0, stream>>>(cand, ctl, roi, sbox);
  mask_kernel<<<dim3(94, 94), 64, 0, stream>>>(sbox, Mmask);
  resolve_kernel<<<1, 64, 0, stream>>>(Mmask, ctl, sbox, rois);
}